// Round 9
// baseline (243.561 us; speedup 1.0000x reference)
//
#include <hip/hip_runtime.h>
#include <math.h>

// B=8, N=2048, Fin=Fout=512, fp32 in/out. bf16 MFMA internally.
// adj = x·(W1^T·W2)·x^T  (Gt precomputed, log2e folded) ->
// out[n,o] = sum_m exp2(q[n,:]·x[m,:]) * (sup[m,o]/D[m]), D[m] = colsum of E.
#define BB 8
#define NN 2048
#define FF 512
#define CROW 1024
#define LOG2E 1.4426950408889634f

typedef __attribute__((ext_vector_type(8))) short short8;
typedef __attribute__((ext_vector_type(4))) float floatx4;
typedef __attribute__((ext_vector_type(2))) float float2v;
typedef __attribute__((ext_vector_type(2))) __bf16 bf16x2;

__device__ __forceinline__ unsigned short f2bf(float f) {
    union { float f; unsigned u; } v; v.f = f;
    unsigned r = v.u + 0x7FFFu + ((v.u >> 16) & 1u);
    return (unsigned short)(r >> 16);
}

__device__ __forceinline__ float fexp2(float x) {
#if __has_builtin(__builtin_amdgcn_exp2f)
    return __builtin_amdgcn_exp2f(x);
#else
    return __expf(x * 0.69314718056f);
#endif
}

__device__ __forceinline__ void pk_store(unsigned short* p0, unsigned short* p1,
                                         float a, float b) {
    union { bf16x2 h; unsigned short s[2]; } u;
    float2v v; v.x = a; v.y = b;
    u.h = __builtin_convertvector(v, bf16x2);
    *p0 = u.s[0]; *p1 = u.s[1];
}

// ---------------------------------------------------------------------------
// BT-GEMM, bf16 16x16x32 MFMA (r8 config, best measured): C[i,j] = A[i,:]·B[j,:]
// Block 128x128, BK=64 (32 KB LDS), 128 thr = 2 waves, wave tile 128x64.
// Staging/read XOR swizzle measured conflict-free (r5/r6/r8: 0 conflicts).
// modes: 0 = fp32 out + bias[j]; 1 = bf16 out; 2 = bf16 exp2(out) + Dsum[j] colsum
// ---------------------------------------------------------------------------
__global__ __launch_bounds__(128, 2) void gemm_bt16(
    const unsigned short* __restrict__ A, const unsigned short* __restrict__ B,
    void* __restrict__ Cv, const float* __restrict__ bias, float* __restrict__ Dsum,
    int K, int a_ld, int b_ld, int ldc,
    long a_batch, long b_batch, long c_batch, int mode)
{
    __shared__ __align__(16) unsigned short Alds[128 * 64];
    __shared__ __align__(16) unsigned short Blds[128 * 64];

    const int tid  = threadIdx.x;
    const int lane = tid & 63;
    const int bz   = blockIdx.z;

    const int m0 = blockIdx.y * 128;
    const int n0 = blockIdx.x * 128;

    const unsigned short* Aptr = A + (long)bz * a_batch + (long)m0 * a_ld;
    const unsigned short* Bptr = B + (long)bz * b_batch + (long)n0 * b_ld;

    const int wn   = (tid >> 6) * 64;
    const int fl   = lane & 15;
    const int quad = lane >> 4;

    int offA[8], offB[8];
    #pragma unroll
    for (int s = 0; s < 8; ++s) {
        const int c = s * 128 + tid;
        const int row = c >> 3;
        const int kq = ((c & 7) ^ (row & 7)) << 3;
        offA[s] = row * a_ld + kq;
        offB[s] = row * b_ld + kq;
    }

    floatx4 acc[8][4] = {};

    for (int k0 = 0; k0 < K; k0 += 64) {
        #pragma unroll
        for (int s = 0; s < 8; ++s) {
            __builtin_amdgcn_global_load_lds(
                (const __attribute__((address_space(1))) void*)(Aptr + offA[s]),
                (__attribute__((address_space(3))) void*)&Alds[(s * 128 + tid - lane) * 8], 16, 0, 0);
            __builtin_amdgcn_global_load_lds(
                (const __attribute__((address_space(1))) void*)(Bptr + offB[s]),
                (__attribute__((address_space(3))) void*)&Blds[(s * 128 + tid - lane) * 8], 16, 0, 0);
        }
        Aptr += 64; Bptr += 64;
        __syncthreads();

        #pragma unroll
        for (int s = 0; s < 2; ++s) {
            const int slot = ((s * 4 + quad) ^ (fl & 7)) * 8;
            short8 af[8], bf[4];
            #pragma unroll
            for (int j = 0; j < 4; ++j)
                bf[j] = *(const short8*)&Blds[(wn + j * 16 + fl) * 64 + slot];
            #pragma unroll
            for (int i = 0; i < 8; ++i)
                af[i] = *(const short8*)&Alds[(i * 16 + fl) * 64 + slot];
            #pragma unroll
            for (int i = 0; i < 8; ++i)
                #pragma unroll
                for (int j = 0; j < 4; ++j)
                    acc[i][j] = __builtin_amdgcn_mfma_f32_16x16x32_bf16(af[i], bf[j], acc[i][j], 0, 0, 0);
        }
        __syncthreads();
    }

    if (mode == 0) {
        float* Cb = (float*)Cv + (long)bz * c_batch;
        #pragma unroll
        for (int j = 0; j < 4; ++j) {
            const int ng = n0 + wn + j * 16 + fl;
            const float badd = bias ? bias[ng] : 0.0f;
            #pragma unroll
            for (int i = 0; i < 8; ++i) {
                const int mg = m0 + i * 16 + quad * 4;
                #pragma unroll
                for (int r = 0; r < 4; ++r)
                    Cb[(long)(mg + r) * ldc + ng] = acc[i][j][r] + badd;
            }
        }
    } else if (mode == 1) {
        unsigned short* Cb = (unsigned short*)Cv + (long)bz * c_batch;
        #pragma unroll
        for (int j = 0; j < 4; ++j) {
            const int ng = n0 + wn + j * 16 + fl;
            #pragma unroll
            for (int i = 0; i < 8; ++i) {
                const int mg = m0 + i * 16 + quad * 4;
                pk_store(&Cb[(long)(mg + 0) * ldc + ng], &Cb[(long)(mg + 1) * ldc + ng],
                         acc[i][j][0], acc[i][j][1]);
                pk_store(&Cb[(long)(mg + 2) * ldc + ng], &Cb[(long)(mg + 3) * ldc + ng],
                         acc[i][j][2], acc[i][j][3]);
            }
        }
    } else {
        unsigned short* Cb = (unsigned short*)Cv + (long)bz * c_batch;
        float* Db = Dsum + (long)bz * NN;
        #pragma unroll
        for (int i = 0; i < 8; ++i)
            #pragma unroll
            for (int j = 0; j < 4; ++j)
                #pragma unroll
                for (int r = 0; r < 4; ++r)
                    acc[i][j][r] = fexp2(acc[i][j][r]);
        #pragma unroll
        for (int j = 0; j < 4; ++j) {
            const int ng = n0 + wn + j * 16 + fl;
            float csum = 0.f;
            #pragma unroll
            for (int i = 0; i < 8; ++i) {
                const int mg = m0 + i * 16 + quad * 4;
                csum += acc[i][j][0] + acc[i][j][1] + acc[i][j][2] + acc[i][j][3];
                pk_store(&Cb[(long)(mg + 0) * ldc + ng], &Cb[(long)(mg + 1) * ldc + ng],
                         acc[i][j][0], acc[i][j][1]);
                pk_store(&Cb[(long)(mg + 2) * ldc + ng], &Cb[(long)(mg + 3) * ldc + ng],
                         acc[i][j][2], acc[i][j][3]);
            }
            csum += __shfl_xor(csum, 16);
            csum += __shfl_xor(csum, 32);
            if (quad == 0) atomicAdd(&Db[ng], csum);
        }
    }
}

// x -> bf16 (8 elems/thread); first 16384 threads also zero Dsum.
__global__ __launch_bounds__(256) void convert_x(
    const float* __restrict__ x, unsigned short* __restrict__ xb,
    float* __restrict__ Dsum)
{
    const long t = (long)blockIdx.x * 256 + threadIdx.x;
    if (t < BB * NN) Dsum[t] = 0.0f;
    const long i = t * 8;
    float4 a = *(const float4*)(x + i);
    float4 b = *(const float4*)(x + i + 4);
    union { bf16x2 h[4]; short8 s8; } u;
    float2v v;
    v.x = a.x; v.y = a.y; u.h[0] = __builtin_convertvector(v, bf16x2);
    v.x = a.z; v.y = a.w; u.h[1] = __builtin_convertvector(v, bf16x2);
    v.x = b.x; v.y = b.y; u.h[2] = __builtin_convertvector(v, bf16x2);
    v.x = b.z; v.y = b.w; u.h[3] = __builtin_convertvector(v, bf16x2);
    *(short8*)(xb + i) = u.s8;
}

// three 512x512 transposes: z=0: w_one*log2e -> w1T; z=1: w_two -> w2T;
// z=2: weight -> wT. out[o,f] = bf16(in[f,o]*sc).
__global__ __launch_bounds__(256) void transpose3(
    const float* __restrict__ w1, const float* __restrict__ w2,
    const float* __restrict__ wgt,
    unsigned short* __restrict__ w1T, unsigned short* __restrict__ w2T,
    unsigned short* __restrict__ wT)
{
    __shared__ float t[32][33];
    const int tx = threadIdx.x & 31, ty = threadIdx.x >> 5;
    const int x0 = blockIdx.x * 32, y0 = blockIdx.y * 32;
    const float* in; unsigned short* out; float sc = 1.0f;
    if (blockIdx.z == 0) { in = w1; out = w1T; sc = LOG2E; }
    else if (blockIdx.z == 1) { in = w2; out = w2T; }
    else { in = wgt; out = wT; }
    #pragma unroll
    for (int k = 0; k < 32; k += 8)
        t[ty + k][tx] = in[(long)(y0 + ty + k) * FF + x0 + tx];
    __syncthreads();
    #pragma unroll
    for (int k = 0; k < 32; k += 8)
        out[(long)(x0 + ty + k) * FF + y0 + tx] = f2bf(t[tx][ty + k] * sc);
}

// supT[o,m] = bf16( sup[m,o] / D[m] ); sup[m,o] = Call[m*CROW + 512 + o] (bf16).
__global__ __launch_bounds__(256) void scale_transpose(
    const unsigned short* __restrict__ Call, const float* __restrict__ D,
    unsigned short* __restrict__ supT, int batch0)
{
    __shared__ float t[32][33];
    __shared__ float rD[32];
    const int tx = threadIdx.x & 31, ty = threadIdx.x >> 5;
    const int mt = blockIdx.x * 32, ot = blockIdx.y * 32;
    const int b = batch0 + blockIdx.z;
    const unsigned short* Cb = Call + (long)b * NN * CROW;
    unsigned short* Tb = supT + (long)b * NN * FF;
    if (threadIdx.x < 32) rD[threadIdx.x] = 1.0f / D[(long)b * NN + mt + threadIdx.x];
    __syncthreads();
    #pragma unroll
    for (int k = 0; k < 32; k += 8) {
        unsigned short u = Cb[(long)(mt + ty + k) * CROW + 512 + ot + tx];
        union { unsigned uu; float f; } cv; cv.uu = ((unsigned)u) << 16;
        t[ty + k][tx] = cv.f;
    }
    __syncthreads();
    #pragma unroll
    for (int k = 0; k < 32; k += 8)
        Tb[(long)(ot + ty + k) * NN + mt + tx] = f2bf(t[tx][ty + k] * rD[tx]);
}

extern "C" void kernel_launch(void* const* d_in, const int* in_sizes, int n_in,
                              void* d_out, int out_size, void* d_ws, size_t ws_size,
                              hipStream_t stream)
{
    const float* x      = (const float*)d_in[0];
    const float* weight = (const float*)d_in[1];
    const float* bias   = (const float*)d_in[2];
    const float* w_one  = (const float*)d_in[3];
    const float* w_two  = (const float*)d_in[4];
    float* out = (float*)d_out;

    const long NF  = (long)NN * FF;      // 1,048,576
    const long NN2 = (long)NN * NN;      // 4,194,304

    // workspace carve
    char* p = (char*)d_ws;
    unsigned short* xb    = (unsigned short*)p; p += (size_t)BB * NF * 2;          // 16 MB
    unsigned short* w1T   = (unsigned short*)p; p += (size_t)FF * FF * 2;          // 0.5 MB
    unsigned short* w2T   = (unsigned short*)p; p += (size_t)FF * FF * 2;          // 0.5 MB
    unsigned short* Wall2 = (unsigned short*)p; p += (size_t)CROW * FF * 2;        // 1 MB ([Gt|wT])
    unsigned short* Call  = (unsigned short*)p; p += (size_t)BB * NN * CROW * 2;   // 32 MB
    unsigned short* supT  = (unsigned short*)p; p += (size_t)BB * NF * 2;          // 16 MB
    float*          Dsum  = (float*)p;          p += (size_t)BB * NN * 4;          // 64 KB
    unsigned short* E     = (unsigned short*)p;                                    // 64 MB (full) / 8 MB (batch)
    unsigned short* Gt = Wall2;                       // rows 0..511
    unsigned short* wT = Wall2 + (size_t)FF * FF;     // rows 512..1023

    const size_t fixed = (size_t)(p - (char*)d_ws);
    const bool full = ws_size >= fixed + (size_t)BB * NN2 * 2;

    dim3 blk(256);
    dim3 gblk(128);

    // 1) converts (+Dsum zero fused); weight transposes
    convert_x<<<dim3(4096), blk, 0, stream>>>(x, xb, Dsum);
    transpose3<<<dim3(16, 16, 3), blk, 0, stream>>>(w_one, w_two, weight, w1T, w2T, wT);

    // 2) Gt[g,f] = sum_e w2T[g,e]·w1T[f,e]  (= (W1^T W2)^T, log2e folded)
    gemm_bt16<<<dim3(4, 4, 1), gblk, 0, stream>>>(
        w2T, w1T, Gt, nullptr, nullptr, FF, FF, FF, FF, 0, 0, 0, 1);

    // 3) Call[n,j] = xb[n,:]·Wall2[j,:]  (j<512: q, j>=512: sup)
    gemm_bt16<<<dim3(CROW / 128, NN / 128, BB), gblk, 0, stream>>>(
        xb, Wall2, Call, nullptr, nullptr, FF,
        FF, FF, CROW, NF, 0, (long)NN * CROW, 1);

    if (full) {
        // 4) E[n,m] = exp2(q[n,:]·xb[m,:]); Dsum[b,m] += colsums
        gemm_bt16<<<dim3(NN / 128, NN / 128, BB), gblk, 0, stream>>>(
            Call, xb, E, nullptr, Dsum, FF,
            CROW, FF, NN, (long)NN * CROW, NF, NN2, 2);
        // 5) supT[o,m] = sup[m,o]/D[m]
        scale_transpose<<<dim3(NN / 32, FF / 32, BB), blk, 0, stream>>>(Call, Dsum, supT, 0);
        // 6) out[n,o] = E[n,:]·supT[o,:] + bias[o]  (K=2048)
        gemm_bt16<<<dim3(FF / 128, NN / 128, BB), gblk, 0, stream>>>(
            E, supT, out, bias, nullptr, NN,
            NN, NN, FF, NN2, NF, NF, 0);
    } else {
        for (int b = 0; b < BB; ++b) {
            gemm_bt16<<<dim3(NN / 128, NN / 128, 1), gblk, 0, stream>>>(
                Call + (size_t)b * NN * CROW, xb + (size_t)b * NF, E, nullptr,
                Dsum + (size_t)b * NN, FF, CROW, FF, NN, 0, 0, 0, 2);
            scale_transpose<<<dim3(NN / 32, FF / 32, 1), blk, 0, stream>>>(Call, Dsum, supT, b);
            gemm_bt16<<<dim3(FF / 128, NN / 128, 1), gblk, 0, stream>>>(
                E, supT + (size_t)b * NF, out + (size_t)b * NF, bias, nullptr, NN,
                NN, NN, FF, 0, 0, 0, 0);
        }
    }
}